// Round 2
// baseline (391.109 us; speedup 1.0000x reference)
//
#include <hip/hip_runtime.h>
#include <hip/hip_bf16.h>

// SGC: out = (D^-1/2 (A+I) D^-1/2)^3 X W + b
// Strategy: out = A_hat^3 (X W) + b  (project 256->64 first, propagate 64-wide).
// Runtime dtype probes: edge_index int64 vs int32; x/W/b fp32 vs bf16.
// All compute fp32; output written fp32 (reference output dtype).

#define NFEAT 256
#define NCLS  64
#define GR    32   // rows per block in GEMM

__device__ __forceinline__ float bf2f(unsigned int u) {
    return __uint_as_float(u << 16);
}

// ---------- edge dtype detection (int64 vs int32) ----------
__global__ void k_detect(const void* ei, int twoE, int nnodes, int* flag) {
    __shared__ int ok;
    if (threadIdx.x == 0) ok = 1;
    __syncthreads();
    const long long* p = (const long long*)ei;
    int nchk = 2048;
    if (nchk > twoE / 2) nchk = twoE / 2;
    for (int i = threadIdx.x; i < nchk; i += 256) {
        long long v = p[i];
        if (v < 0 || v >= (long long)nnodes) ok = 0;
    }
    __syncthreads();
    if (threadIdx.x == 0) *flag = ok;  // 1 = int64, 0 = int32
}

// ---------- float dtype detection (fp32 vs packed bf16) ----------
// Low 16 bits of each 32-bit word: for fp32 data = mantissa noise (frequently
// exponent>=151 when read as bf16); for bf16 data = a genuine small value.
__global__ void k_fdetect(const unsigned int* __restrict__ x, int nwords, int* fflag) {
    __shared__ int wild;
    if (threadIdx.x == 0) wild = 0;
    __syncthreads();
    int lim = nwords < 4096 ? nwords : 4096;
    int local = 0;
    for (int i = threadIdx.x; i < lim; i += 256) {
        unsigned int lo = x[i] & 0xffffu;
        unsigned int expf = (lo >> 7) & 0xffu;
        if (expf >= 0x97u) local++;  // |v| >= 2^24 (incl. inf/nan) as bf16
    }
    if (local) atomicAdd(&wild, local);
    __syncthreads();
    if (threadIdx.x == 0) *fflag = (wild < 8) ? 1 : 0;  // 1 = bf16, 0 = fp32
}

__global__ void k_extract(const void* ei, int twoE, const int* __restrict__ flag,
                          int* __restrict__ out32) {
    int i = blockIdx.x * blockDim.x + threadIdx.x;
    if (i < twoE) {
        if (*flag)
            out32[i] = (int)((const long long*)ei)[i];
        else
            out32[i] = ((const int*)ei)[i];
    }
}

// ---------- W, b -> fp32 workspace copies ----------
__global__ void k_wconv(const void* __restrict__ Wg, const void* __restrict__ Bg,
                        const int* __restrict__ fflag,
                        float* __restrict__ Wc, float* __restrict__ bc) {
    int i = blockIdx.x * 256 + threadIdx.x;
    bool isbf = (*fflag != 0);
    if (i < NFEAT * NCLS) {
        Wc[i] = isbf ? bf2f(((const unsigned short*)Wg)[i])
                     : ((const float*)Wg)[i];
    }
    int j = i - NFEAT * NCLS;
    if (j >= 0 && j < NCLS) {
        bc[j] = isbf ? bf2f(((const unsigned short*)Bg)[j])
                     : ((const float*)Bg)[j];
    }
}

// ---------- degree / dinv ----------
__global__ void k_hist(const int* __restrict__ dst, int E, int* __restrict__ cnt) {
    int e = blockIdx.x * blockDim.x + threadIdx.x;
    if (e < E) atomicAdd(&cnt[dst[e]], 1);
}

__global__ void k_dinv(const int* __restrict__ cnt, float* __restrict__ dinv, int n) {
    int i = blockIdx.x * blockDim.x + threadIdx.x;
    if (i < n) dinv[i] = 1.0f / sqrtf((float)(cnt[i] + 1));  // +1 = self loop
}

// ---------- two-level exclusive scan over cnt -> rowptr ----------
__global__ void k_scan1(const int* __restrict__ cnt, int n, int* __restrict__ bsum) {
    __shared__ int s[256];
    int i = blockIdx.x * 256 + threadIdx.x;
    s[threadIdx.x] = (i < n) ? cnt[i] : 0;
    __syncthreads();
    for (int off = 128; off > 0; off >>= 1) {
        if (threadIdx.x < off) s[threadIdx.x] += s[threadIdx.x + off];
        __syncthreads();
    }
    if (threadIdx.x == 0) bsum[blockIdx.x] = s[0];
}

__global__ void k_scan2(int* __restrict__ bsum, int nb, int* __restrict__ total_out) {
    __shared__ int s[256];
    int t = threadIdx.x;
    int v = (t < nb) ? bsum[t] : 0;
    s[t] = v;
    __syncthreads();
    for (int off = 1; off < 256; off <<= 1) {
        int x = (t >= off) ? s[t - off] : 0;
        __syncthreads();
        s[t] += x;
        __syncthreads();
    }
    if (t < nb) bsum[t] = s[t] - v;      // exclusive
    if (t == nb - 1) *total_out = s[t];  // rowptr[N] = E
}

__global__ void k_scan3(const int* __restrict__ cnt, int n, const int* __restrict__ bsum,
                        int* __restrict__ rowptr, int* __restrict__ cursor) {
    __shared__ int s[256];
    int t = threadIdx.x;
    int i = blockIdx.x * 256 + t;
    int v = (i < n) ? cnt[i] : 0;
    s[t] = v;
    __syncthreads();
    for (int off = 1; off < 256; off <<= 1) {
        int x = (t >= off) ? s[t - off] : 0;
        __syncthreads();
        s[t] += x;
        __syncthreads();
    }
    if (i < n) {
        int r = bsum[blockIdx.x] + s[t] - v;
        rowptr[i] = r;
        cursor[i] = r;
    }
}

// ---------- CSR scatter: edges[p] = (src, dinv[src]*dinv[dst]) ----------
__global__ void k_scatter(const int* __restrict__ src, const int* __restrict__ dst, int E,
                          const float* __restrict__ dinv, int* __restrict__ cursor,
                          int2* __restrict__ edges) {
    int e = blockIdx.x * blockDim.x + threadIdx.x;
    if (e < E) {
        int s = src[e], d = dst[e];
        int p = atomicAdd(&cursor[d], 1);
        edges[p] = make_int2(s, __float_as_int(dinv[s] * dinv[d]));
    }
}

// ---------- Y0 = X @ W (fp32 out; X dtype per fflag, W preconverted) ----------
__launch_bounds__(256)
__global__ void k_xw(const void* __restrict__ Xg, const float* __restrict__ Wc,
                     float* __restrict__ Y, int N, const int* __restrict__ fflag) {
    __shared__ float Xs[GR * NFEAT];  // 32 KB
    const int t = threadIdx.x;
    const int row0 = blockIdx.x * GR;
    const bool isbf = (*fflag != 0);

    if (isbf) {
        const unsigned int* Xu = (const unsigned int*)Xg;  // bf16 pairs
        for (int i = t * 4; i < GR * NFEAT; i += 1024) {
            int gr = row0 + (i >> 8);
            float4 f = make_float4(0.f, 0.f, 0.f, 0.f);
            if (gr < N) {
                uint2 raw = *(const uint2*)(Xu + ((size_t)gr * NFEAT + (i & 255)) / 2);
                f.x = bf2f(raw.x & 0xffffu); f.y = bf2f(raw.x >> 16);
                f.z = bf2f(raw.y & 0xffffu); f.w = bf2f(raw.y >> 16);
            }
            *(float4*)&Xs[i] = f;
        }
    } else {
        const float* Xf = (const float*)Xg;
        for (int i = t * 4; i < GR * NFEAT; i += 1024) {
            int gr = row0 + (i >> 8);
            float4 f = make_float4(0.f, 0.f, 0.f, 0.f);
            if (gr < N) f = *(const float4*)(Xf + (size_t)gr * NFEAT + (i & 255));
            *(float4*)&Xs[i] = f;
        }
    }
    __syncthreads();

    const int wv = t >> 6, lane = t & 63;
    const int rb = wv * 8;  // 4 waves x 8 rows = 32 rows
    float acc[8] = {0.f, 0.f, 0.f, 0.f, 0.f, 0.f, 0.f, 0.f};
    for (int kt = 0; kt < NFEAT; kt += 4) {
        float w0 = Wc[(kt + 0) * NCLS + lane];
        float w1 = Wc[(kt + 1) * NCLS + lane];
        float w2 = Wc[(kt + 2) * NCLS + lane];
        float w3 = Wc[(kt + 3) * NCLS + lane];
#pragma unroll
        for (int r = 0; r < 8; ++r) {
            float4 x = *(const float4*)&Xs[(rb + r) * NFEAT + kt];  // wave-broadcast
            acc[r] = fmaf(x.x, w0, acc[r]);
            acc[r] = fmaf(x.y, w1, acc[r]);
            acc[r] = fmaf(x.z, w2, acc[r]);
            acc[r] = fmaf(x.w, w3, acc[r]);
        }
    }
#pragma unroll
    for (int r = 0; r < 8; ++r) {
        int gr = row0 + rb + r;
        if (gr < N) Y[(size_t)gr * NCLS + lane] = acc[r];
    }
}

// ---------- propagation hop: one wave per node, lane = feature ----------
__launch_bounds__(256)
__global__ void k_prop(const float* __restrict__ Yin, const int* __restrict__ rowptr,
                       const int2* __restrict__ edges, const float* __restrict__ dinv,
                       float* __restrict__ Yout, int N,
                       const float* __restrict__ bias) {  // bias!=nullptr on last hop
    int node = blockIdx.x * 4 + (threadIdx.x >> 6);
    if (node >= N) return;
    int lane = threadIdx.x & 63;
    float di = dinv[node];
    float acc = di * di * Yin[(size_t)node * NCLS + lane];  // self-loop
    float acc2 = 0.f;
    int e = rowptr[node];
    const int e1 = rowptr[node + 1];
    for (; e + 1 < e1; e += 2) {
        int2 p0 = edges[e];
        int2 p1 = edges[e + 1];
        acc  = fmaf(__int_as_float(p0.y), Yin[(size_t)p0.x * NCLS + lane], acc);
        acc2 = fmaf(__int_as_float(p1.y), Yin[(size_t)p1.x * NCLS + lane], acc2);
    }
    if (e < e1) {
        int2 p = edges[e];
        acc = fmaf(__int_as_float(p.y), Yin[(size_t)p.x * NCLS + lane], acc);
    }
    acc += acc2;
    if (bias) acc += bias[lane];
    Yout[(size_t)node * NCLS + lane] = acc;
}

extern "C" void kernel_launch(void* const* d_in, const int* in_sizes, int n_in,
                              void* d_out, int out_size, void* d_ws, size_t ws_size,
                              hipStream_t stream) {
    const void* X  = d_in[0];
    const void* EI = d_in[1];
    const void* W  = d_in[2];
    const void* B  = d_in[3];
    float* out = (float*)d_out;

    const int N = in_sizes[0] / NFEAT;  // 50000
    const int twoE = in_sizes[1];       // 1,600,000
    const int E = twoE / 2;             // 800,000

    // ---- carve workspace (256B aligned) ----
    char* p = (char*)d_ws;
    auto alloc = [&](size_t bytes) -> char* {
        char* q = p;
        p += (bytes + 255) & ~(size_t)255;
        return q;
    };
    int*   flag   = (int*)alloc(4);
    int*   fflag  = (int*)alloc(4);
    int*   ei32   = (int*)alloc((size_t)twoE * 4);  // src then dst
    int*   cnt    = (int*)alloc((size_t)N * 4);
    int*   rowptr = (int*)alloc((size_t)(N + 1) * 4);
    int*   cursor = (int*)alloc((size_t)N * 4);
    float* dinv   = (float*)alloc((size_t)N * 4);
    int*   bsum   = (int*)alloc(256 * 4);
    float* Wc     = (float*)alloc((size_t)NFEAT * NCLS * 4);
    float* bc     = (float*)alloc((size_t)NCLS * 4);
    int2*  edges  = (int2*)alloc((size_t)E * 8);
    float* Y0     = (float*)alloc((size_t)N * NCLS * 4);
    float* Y1     = (float*)alloc((size_t)N * NCLS * 4);

    const int* src = ei32;
    const int* dst = ei32 + E;

    hipMemsetAsync(cnt, 0, (size_t)N * 4, stream);

    k_detect<<<1, 256, 0, stream>>>(EI, twoE, N, flag);
    k_fdetect<<<1, 256, 0, stream>>>((const unsigned int*)X, in_sizes[0] / 2, fflag);

    int nb_2e = (twoE + 255) / 256;
    k_extract<<<nb_2e, 256, 0, stream>>>(EI, twoE, flag, ei32);
    k_wconv<<<(NFEAT * NCLS + NCLS + 255) / 256, 256, 0, stream>>>(W, B, fflag, Wc, bc);

    int nb_e = (E + 255) / 256;
    int nb_n = (N + 255) / 256;  // 196 blocks, fits single-block scan2
    k_hist<<<nb_e, 256, 0, stream>>>(dst, E, cnt);
    k_dinv<<<nb_n, 256, 0, stream>>>(cnt, dinv, N);
    k_scan1<<<nb_n, 256, 0, stream>>>(cnt, N, bsum);
    k_scan2<<<1, 256, 0, stream>>>(bsum, nb_n, rowptr + N);
    k_scan3<<<nb_n, 256, 0, stream>>>(cnt, N, bsum, rowptr, cursor);
    k_scatter<<<nb_e, 256, 0, stream>>>(src, dst, E, dinv, cursor, edges);

    k_xw<<<(N + GR - 1) / GR, 256, 0, stream>>>(X, Wc, Y0, N, fflag);

    int nb_p = (N + 3) / 4;
    k_prop<<<nb_p, 256, 0, stream>>>(Y0, rowptr, edges, dinv, Y1, N, nullptr);
    k_prop<<<nb_p, 256, 0, stream>>>(Y1, rowptr, edges, dinv, Y0, N, nullptr);
    k_prop<<<nb_p, 256, 0, stream>>>(Y0, rowptr, edges, dinv, out, N, bc);
}

// Round 3
// 311.426 us; speedup vs baseline: 1.2559x; 1.2559x over previous
//
#include <hip/hip_runtime.h>
#include <hip/hip_bf16.h>

// SGC: out = (D^-1/2 (A+I) D^-1/2)^3 X W + b
// Strategy: out = A_hat^3 (X W) + b  (project 256->64 first, propagate 64-wide).
// Runtime dtype probes: edge_index int64 vs int32; x/W/b fp32 vs bf16.
// R3: MFMA bf16 GEMM for XW (on-the-fly fp32->bf16), unroll-4 gather in k_prop,
//     fused small kernels (detect2, extract+hist, dinv folded into scan3).

#define NFEAT 256
#define NCLS  64

typedef __attribute__((ext_vector_type(8))) short bf16x8;
typedef __attribute__((ext_vector_type(4))) float f32x4;

__device__ __forceinline__ float bf2f(unsigned int u) {
    return __uint_as_float(u << 16);
}
__device__ __forceinline__ unsigned short f2bf(float f) {
    unsigned int u = __float_as_uint(f);
    unsigned int r = u + 0x7fffu + ((u >> 16) & 1u);  // RNE
    return (unsigned short)(r >> 16);
}

// ---------- fused dtype detection: block 0 = edges (int64 vs int32),
// ----------                        block 1 = floats (fp32 vs bf16) ----------
__global__ void k_detect2(const void* ei, int twoE, int nnodes,
                          const unsigned int* __restrict__ x, int nwords,
                          int* flag, int* fflag) {
    __shared__ int acc;
    if (threadIdx.x == 0) acc = 0;
    __syncthreads();
    if (blockIdx.x == 0) {
        const long long* p = (const long long*)ei;
        int nchk = 2048;
        if (nchk > twoE / 2) nchk = twoE / 2;
        int bad = 0;
        for (int i = threadIdx.x; i < nchk; i += 256) {
            long long v = p[i];
            if (v < 0 || v >= (long long)nnodes) bad++;
        }
        if (bad) atomicAdd(&acc, bad);
        __syncthreads();
        if (threadIdx.x == 0) *flag = (acc == 0) ? 1 : 0;  // 1 = int64
    } else {
        int lim = nwords < 4096 ? nwords : 4096;
        int wild = 0;
        for (int i = threadIdx.x; i < lim; i += 256) {
            unsigned int lo = x[i] & 0xffffu;
            unsigned int expf = (lo >> 7) & 0xffu;
            if (expf >= 0x97u) wild++;  // |v| >= 2^24 as bf16 -> fp32 mantissa noise
        }
        if (wild) atomicAdd(&acc, wild);
        __syncthreads();
        if (threadIdx.x == 0) *fflag = (acc < 8) ? 1 : 0;  // 1 = bf16
    }
}

// ---------- extract edges to int32 + in-degree histogram (dst half) ----------
__global__ void k_extract_hist(const void* ei, int twoE, int E,
                               const int* __restrict__ flag,
                               int* __restrict__ out32, int* __restrict__ cnt) {
    int i = blockIdx.x * blockDim.x + threadIdx.x;
    if (i < twoE) {
        int v = (*flag) ? (int)((const long long*)ei)[i] : ((const int*)ei)[i];
        out32[i] = v;
        if (i >= E) atomicAdd(&cnt[v], 1);
    }
}

// ---------- W -> bf16 transposed [n][k] + bias fp32 ----------
__global__ void k_wconv(const void* __restrict__ Wg, const void* __restrict__ Bg,
                        const int* __restrict__ fflag,
                        unsigned short* __restrict__ Wt, float* __restrict__ bc) {
    int i = blockIdx.x * 256 + threadIdx.x;
    bool isbf = (*fflag != 0);
    if (i < NFEAT * NCLS) {
        int n = i >> 8, k = i & 255;  // Wt[n][k] = W[k][n]
        Wt[i] = isbf ? ((const unsigned short*)Wg)[k * NCLS + n]
                     : f2bf(((const float*)Wg)[k * NCLS + n]);
    }
    int j = i - NFEAT * NCLS;
    if (j >= 0 && j < NCLS) {
        bc[j] = isbf ? bf2f(((const unsigned short*)Bg)[j])
                     : ((const float*)Bg)[j];
    }
}

// ---------- two-level exclusive scan over cnt -> rowptr (+dinv) ----------
__global__ void k_scan1(const int* __restrict__ cnt, int n, int* __restrict__ bsum) {
    __shared__ int s[256];
    int i = blockIdx.x * 256 + threadIdx.x;
    s[threadIdx.x] = (i < n) ? cnt[i] : 0;
    __syncthreads();
    for (int off = 128; off > 0; off >>= 1) {
        if (threadIdx.x < off) s[threadIdx.x] += s[threadIdx.x + off];
        __syncthreads();
    }
    if (threadIdx.x == 0) bsum[blockIdx.x] = s[0];
}

__global__ void k_scan2(int* __restrict__ bsum, int nb, int* __restrict__ total_out) {
    __shared__ int s[256];
    int t = threadIdx.x;
    int v = (t < nb) ? bsum[t] : 0;
    s[t] = v;
    __syncthreads();
    for (int off = 1; off < 256; off <<= 1) {
        int x = (t >= off) ? s[t - off] : 0;
        __syncthreads();
        s[t] += x;
        __syncthreads();
    }
    if (t < nb) bsum[t] = s[t] - v;      // exclusive
    if (t == nb - 1) *total_out = s[t];  // rowptr[N] = E
}

__global__ void k_scan3(const int* __restrict__ cnt, int n, const int* __restrict__ bsum,
                        int* __restrict__ rowptr, int* __restrict__ cursor,
                        float* __restrict__ dinv) {
    __shared__ int s[256];
    int t = threadIdx.x;
    int i = blockIdx.x * 256 + t;
    int v = (i < n) ? cnt[i] : 0;
    s[t] = v;
    __syncthreads();
    for (int off = 1; off < 256; off <<= 1) {
        int x = (t >= off) ? s[t - off] : 0;
        __syncthreads();
        s[t] += x;
        __syncthreads();
    }
    if (i < n) {
        int r = bsum[blockIdx.x] + s[t] - v;
        rowptr[i] = r;
        cursor[i] = r;
        dinv[i] = 1.0f / sqrtf((float)(v + 1));  // +1 = self loop
    }
}

// ---------- CSR scatter: edges[p] = (src, dinv[src]*dinv[dst]) ----------
__global__ void k_scatter(const int* __restrict__ src, const int* __restrict__ dst, int E,
                          const float* __restrict__ dinv, int* __restrict__ cursor,
                          int2* __restrict__ edges) {
    int e = blockIdx.x * blockDim.x + threadIdx.x;
    if (e < E) {
        int s = src[e], d = dst[e];
        int p = atomicAdd(&cursor[d], 1);
        edges[p] = make_int2(s, __float_as_int(dinv[s] * dinv[d]));
    }
}

// ---------- Y0 = X @ W via MFMA bf16 16x16x32 ----------
// Block = 4 waves; wave w computes rows [blk*64 + 16w, +16) x all 64 cols.
// B fragments pre-swizzled into LDS in per-lane-contiguous frag order:
//   entry e = (ks*4 + nt)*64 + lane, 8 bf16 each -> ds_read_b128 conflict-free.
__launch_bounds__(256)
__global__ void k_xw_mfma(const void* __restrict__ Xg,
                          const unsigned short* __restrict__ Wt,  // [n][k] bf16
                          float* __restrict__ Y, int N, const int* __restrict__ fflag) {
    __shared__ unsigned short Ws[2048 * 8];  // 32 KB: 8 ks x 4 nt x 64 lanes x 8 bf16
    const int t = threadIdx.x;

    // stage W fragments
    for (int it = 0; it < 8; ++it) {
        int e = t + 256 * it;
        int lane_e = e & 63;
        int nt = (e >> 6) & 3;
        int ks = e >> 8;
        int n = nt * 16 + (lane_e & 15);
        int k = ks * 32 + (lane_e >> 4) * 8;
        const unsigned short* srcp = Wt + n * 256 + k;
        ushort4 v0 = *(const ushort4*)srcp;
        ushort4 v1 = *(const ushort4*)(srcp + 4);
        unsigned short* dstp = &Ws[e * 8];
        *(ushort4*)dstp = v0;
        *(ushort4*)(dstp + 4) = v1;
    }
    __syncthreads();

    const int wv = t >> 6, lane = t & 63;
    const int m = lane & 15, q = lane >> 4;
    const int row = blockIdx.x * 64 + wv * 16 + m;  // A-operand row for this lane
    const bool rowok = row < N;
    const bool isbf = (*fflag != 0);

    f32x4 acc0 = {0.f, 0.f, 0.f, 0.f};
    f32x4 acc1 = {0.f, 0.f, 0.f, 0.f};
    f32x4 acc2 = {0.f, 0.f, 0.f, 0.f};
    f32x4 acc3 = {0.f, 0.f, 0.f, 0.f};

    for (int ks = 0; ks < 8; ++ks) {
        const int kk = ks * 32 + q * 8;
        bf16x8 af = {0, 0, 0, 0, 0, 0, 0, 0};
        if (rowok) {
            if (isbf) {
                const unsigned short* xp = (const unsigned short*)Xg + (size_t)row * NFEAT + kk;
                ushort4 lo = *(const ushort4*)xp;
                ushort4 hi = *(const ushort4*)(xp + 4);
                af[0] = (short)lo.x; af[1] = (short)lo.y; af[2] = (short)lo.z; af[3] = (short)lo.w;
                af[4] = (short)hi.x; af[5] = (short)hi.y; af[6] = (short)hi.z; af[7] = (short)hi.w;
            } else {
                const float* xp = (const float*)Xg + (size_t)row * NFEAT + kk;
                float4 f0 = *(const float4*)xp;
                float4 f1 = *(const float4*)(xp + 4);
                af[0] = (short)f2bf(f0.x); af[1] = (short)f2bf(f0.y);
                af[2] = (short)f2bf(f0.z); af[3] = (short)f2bf(f0.w);
                af[4] = (short)f2bf(f1.x); af[5] = (short)f2bf(f1.y);
                af[6] = (short)f2bf(f1.z); af[7] = (short)f2bf(f1.w);
            }
        }
        const unsigned short* wbase = &Ws[(ks * 4) * 512 + lane * 8];
        bf16x8 b0 = *(const bf16x8*)(wbase);
        bf16x8 b1 = *(const bf16x8*)(wbase + 512);
        bf16x8 b2 = *(const bf16x8*)(wbase + 1024);
        bf16x8 b3 = *(const bf16x8*)(wbase + 1536);
        acc0 = __builtin_amdgcn_mfma_f32_16x16x32_bf16(af, b0, acc0, 0, 0, 0);
        acc1 = __builtin_amdgcn_mfma_f32_16x16x32_bf16(af, b1, acc1, 0, 0, 0);
        acc2 = __builtin_amdgcn_mfma_f32_16x16x32_bf16(af, b2, acc2, 0, 0, 0);
        acc3 = __builtin_amdgcn_mfma_f32_16x16x32_bf16(af, b3, acc3, 0, 0, 0);
    }

    // C/D layout: col = lane&15, row = q*4 + reg
    const int rowbase = blockIdx.x * 64 + wv * 16 + q * 4;
#pragma unroll
    for (int i = 0; i < 4; ++i) {
        int gr = rowbase + i;
        if (gr < N) {
            float* yp = Y + (size_t)gr * NCLS + m;
            yp[0]  = acc0[i];
            yp[16] = acc1[i];
            yp[32] = acc2[i];
            yp[48] = acc3[i];
        }
    }
}

// ---------- propagation hop: one wave per node, lane = feature, unroll 4 ----------
__launch_bounds__(256)
__global__ void k_prop(const float* __restrict__ Yin, const int* __restrict__ rowptr,
                       const int2* __restrict__ edges, const float* __restrict__ dinv,
                       float* __restrict__ Yout, int N,
                       const float* __restrict__ bias) {  // bias != nullptr on last hop
    int node = blockIdx.x * 4 + (threadIdx.x >> 6);
    if (node >= N) return;
    int lane = threadIdx.x & 63;
    float di = dinv[node];
    float a0 = di * di * Yin[(size_t)node * NCLS + lane];  // self-loop
    float a1 = 0.f, a2 = 0.f, a3 = 0.f;
    int e = rowptr[node];
    const int e1 = rowptr[node + 1];
    for (; e + 4 <= e1; e += 4) {
        int2 p0 = edges[e];
        int2 p1 = edges[e + 1];
        int2 p2 = edges[e + 2];
        int2 p3 = edges[e + 3];
        float y0 = Yin[(size_t)p0.x * NCLS + lane];
        float y1 = Yin[(size_t)p1.x * NCLS + lane];
        float y2 = Yin[(size_t)p2.x * NCLS + lane];
        float y3 = Yin[(size_t)p3.x * NCLS + lane];
        a0 = fmaf(__int_as_float(p0.y), y0, a0);
        a1 = fmaf(__int_as_float(p1.y), y1, a1);
        a2 = fmaf(__int_as_float(p2.y), y2, a2);
        a3 = fmaf(__int_as_float(p3.y), y3, a3);
    }
    for (; e < e1; ++e) {
        int2 p = edges[e];
        a0 = fmaf(__int_as_float(p.y), Yin[(size_t)p.x * NCLS + lane], a0);
    }
    float acc = (a0 + a1) + (a2 + a3);
    if (bias) acc += bias[lane];
    Yout[(size_t)node * NCLS + lane] = acc;
}

extern "C" void kernel_launch(void* const* d_in, const int* in_sizes, int n_in,
                              void* d_out, int out_size, void* d_ws, size_t ws_size,
                              hipStream_t stream) {
    const void* X  = d_in[0];
    const void* EI = d_in[1];
    const void* W  = d_in[2];
    const void* B  = d_in[3];
    float* out = (float*)d_out;

    const int N = in_sizes[0] / NFEAT;  // 50000
    const int twoE = in_sizes[1];       // 1,600,000
    const int E = twoE / 2;             // 800,000

    // ---- carve workspace (256B aligned) ----
    char* p = (char*)d_ws;
    auto alloc = [&](size_t bytes) -> char* {
        char* q = p;
        p += (bytes + 255) & ~(size_t)255;
        return q;
    };
    int*   flag   = (int*)alloc(4);
    int*   fflag  = (int*)alloc(4);
    int*   ei32   = (int*)alloc((size_t)twoE * 4);  // src then dst
    int*   cnt    = (int*)alloc((size_t)N * 4);
    int*   rowptr = (int*)alloc((size_t)(N + 1) * 4);
    int*   cursor = (int*)alloc((size_t)N * 4);
    float* dinv   = (float*)alloc((size_t)N * 4);
    int*   bsum   = (int*)alloc(256 * 4);
    unsigned short* Wt = (unsigned short*)alloc((size_t)NFEAT * NCLS * 2);  // bf16 [n][k]
    float* bc     = (float*)alloc((size_t)NCLS * 4);
    int2*  edges  = (int2*)alloc((size_t)E * 8);
    float* Y0     = (float*)alloc((size_t)N * NCLS * 4);
    float* Y1     = (float*)alloc((size_t)N * NCLS * 4);

    const int* src = ei32;
    const int* dst = ei32 + E;

    hipMemsetAsync(cnt, 0, (size_t)N * 4, stream);

    k_detect2<<<2, 256, 0, stream>>>(EI, twoE, N, (const unsigned int*)X,
                                     in_sizes[0] / 2, flag, fflag);

    int nb_2e = (twoE + 255) / 256;
    k_extract_hist<<<nb_2e, 256, 0, stream>>>(EI, twoE, E, flag, ei32, cnt);
    k_wconv<<<(NFEAT * NCLS + NCLS + 255) / 256, 256, 0, stream>>>(W, B, fflag, Wt, bc);

    int nb_e = (E + 255) / 256;
    int nb_n = (N + 255) / 256;  // 196 blocks, fits single-block scan2
    k_scan1<<<nb_n, 256, 0, stream>>>(cnt, N, bsum);
    k_scan2<<<1, 256, 0, stream>>>(bsum, nb_n, rowptr + N);
    k_scan3<<<nb_n, 256, 0, stream>>>(cnt, N, bsum, rowptr, cursor, dinv);
    k_scatter<<<nb_e, 256, 0, stream>>>(src, dst, E, dinv, cursor, edges);

    k_xw_mfma<<<(N + 63) / 64, 256, 0, stream>>>(X, Wt, Y0, N, fflag);

    int nb_p = (N + 3) / 4;
    k_prop<<<nb_p, 256, 0, stream>>>(Y0, rowptr, edges, dinv, Y1, N, nullptr);
    k_prop<<<nb_p, 256, 0, stream>>>(Y1, rowptr, edges, dinv, Y0, N, nullptr);
    k_prop<<<nb_p, 256, 0, stream>>>(Y0, rowptr, edges, dinv, out, N, bc);
}

// Round 4
// 257.931 us; speedup vs baseline: 1.5163x; 1.2074x over previous
//
#include <hip/hip_runtime.h>
#include <hip/hip_bf16.h>

// SGC: out = (D^-1/2 (A+I) D^-1/2)^3 X W + b
// R4: ELL adjacency (64 slots/node, src-only 4B entries) built in ONE pass over
//     the raw int64 edge list, fused into the same kernel as the MFMA GEMM
//     (GEMM blocks first, build blocks after -> latency/compute co-schedule).
//     No rowptr/scan/scatter. Intermediate Y in bf16 (halves hop gather bytes).
//     norm recomputed per-edge as dinv[src]*dinv[dst] (dinv is L2-hot, scalar).

#define NFEAT 256
#define NCLS  64
#define ELLW  64   // slots per node; P(deg>=64) ~ 1e-18 for Poisson(16)

typedef __attribute__((ext_vector_type(8))) short bf16x8;
typedef __attribute__((ext_vector_type(4))) float f32x4;

__device__ __forceinline__ float bf2f(unsigned int u) {
    return __uint_as_float(u << 16);
}
__device__ __forceinline__ unsigned short f2bf(float f) {
    unsigned int u = __float_as_uint(f);
    unsigned int r = u + 0x7fffu + ((u >> 16) & 1u);  // RNE
    return (unsigned short)(r >> 16);
}

// ---------- fused dtype detection: block 0 = edges (int64 vs int32),
// ----------                        block 1 = floats (fp32 vs bf16) ----------
__global__ void k_detect2(const void* ei, int twoE, int nnodes,
                          const unsigned int* __restrict__ x, int nwords,
                          int* flag, int* fflag) {
    __shared__ int acc;
    if (threadIdx.x == 0) acc = 0;
    __syncthreads();
    if (blockIdx.x == 0) {
        const long long* p = (const long long*)ei;
        int nchk = 2048;
        if (nchk > twoE / 2) nchk = twoE / 2;
        int bad = 0;
        for (int i = threadIdx.x; i < nchk; i += 256) {
            long long v = p[i];
            if (v < 0 || v >= (long long)nnodes) bad++;
        }
        if (bad) atomicAdd(&acc, bad);
        __syncthreads();
        if (threadIdx.x == 0) *flag = (acc == 0) ? 1 : 0;  // 1 = int64
    } else {
        int lim = nwords < 4096 ? nwords : 4096;
        int wild = 0;
        for (int i = threadIdx.x; i < lim; i += 256) {
            unsigned int lo = x[i] & 0xffffu;
            unsigned int expf = (lo >> 7) & 0xffu;
            if (expf >= 0x97u) wild++;  // fp32 mantissa noise read as bf16
        }
        if (wild) atomicAdd(&acc, wild);
        __syncthreads();
        if (threadIdx.x == 0) *fflag = (acc < 8) ? 1 : 0;  // 1 = bf16
    }
}

// ---------- W -> bf16 transposed [n][k] + bias fp32 ----------
__global__ void k_wconv(const void* __restrict__ Wg, const void* __restrict__ Bg,
                        const int* __restrict__ fflag,
                        unsigned short* __restrict__ Wt, float* __restrict__ bc) {
    int i = blockIdx.x * 256 + threadIdx.x;
    bool isbf = (*fflag != 0);
    if (i < NFEAT * NCLS) {
        int n = i >> 8, k = i & 255;  // Wt[n][k] = W[k][n]
        Wt[i] = isbf ? ((const unsigned short*)Wg)[k * NCLS + n]
                     : f2bf(((const float*)Wg)[k * NCLS + n]);
    }
    int j = i - NFEAT * NCLS;
    if (j >= 0 && j < NCLS) {
        bc[j] = isbf ? bf2f(((const unsigned short*)Bg)[j])
                     : ((const float*)Bg)[j];
    }
}

// ---------- dinv from final degree counts ----------
__global__ void k_dinv(const int* __restrict__ cnt, float* __restrict__ dinv, int n) {
    int i = blockIdx.x * blockDim.x + threadIdx.x;
    if (i < n) dinv[i] = 1.0f / sqrtf((float)(cnt[i] + 1));  // +1 = self loop
}

// ---------- fused: [0, ngemm) = MFMA GEMM blocks, [ngemm, ..) = ELL build ----------
// GEMM: Y0(bf16) = X @ W, 64 rows/block, bf16 16x16x32 MFMA.
// Build: per edge e: r = atomicAdd(cnt[dst],1); ell[dst*ELLW + r] = src.
__launch_bounds__(256)
__global__ void k_fused(const void* __restrict__ Xg,
                        const unsigned short* __restrict__ Wt,  // [n][k] bf16
                        unsigned short* __restrict__ Yb,        // out bf16 [N][64]
                        int N, const int* __restrict__ fflag,
                        const void* __restrict__ ei, int E, const int* __restrict__ flag,
                        int* __restrict__ cnt, int* __restrict__ ell,
                        int ngemm) {
    __shared__ unsigned short Ws[2048 * 8];  // 32 KB: 8 ks x 4 nt x 64 lanes x 8 bf16
    const int t = threadIdx.x;

    if (blockIdx.x >= ngemm) {
        // ---------------- ELL build path ----------------
        int e = (blockIdx.x - ngemm) * 256 + t;
        if (e < E) {
            int s, d;
            if (*flag) {
                s = (int)((const long long*)ei)[e];
                d = (int)((const long long*)ei)[E + e];
            } else {
                s = ((const int*)ei)[e];
                d = ((const int*)ei)[E + e];
            }
            int r = atomicAdd(&cnt[d], 1);
            if (r < ELLW) ell[(size_t)d * ELLW + r] = s;
        }
        return;
    }

    // ---------------- GEMM path ----------------
    // stage W fragments: entry idx = (ks*4 + nt)*64 + lane, 8 bf16 each
    for (int it = 0; it < 8; ++it) {
        int idx = t + 256 * it;
        int lane_e = idx & 63;
        int nt = (idx >> 6) & 3;
        int ks = idx >> 8;
        int n = nt * 16 + (lane_e & 15);
        int k = ks * 32 + (lane_e >> 4) * 8;
        const unsigned short* srcp = Wt + n * 256 + k;
        ushort4 v0 = *(const ushort4*)srcp;
        ushort4 v1 = *(const ushort4*)(srcp + 4);
        unsigned short* dstp = &Ws[idx * 8];
        *(ushort4*)dstp = v0;
        *(ushort4*)(dstp + 4) = v1;
    }
    __syncthreads();

    const int wv = t >> 6, lane = t & 63;
    const int m = lane & 15, q = lane >> 4;
    const int row = blockIdx.x * 64 + wv * 16 + m;  // A-operand row for this lane
    const bool rowok = row < N;
    const bool isbf = (*fflag != 0);

    f32x4 acc0 = {0.f, 0.f, 0.f, 0.f};
    f32x4 acc1 = {0.f, 0.f, 0.f, 0.f};
    f32x4 acc2 = {0.f, 0.f, 0.f, 0.f};
    f32x4 acc3 = {0.f, 0.f, 0.f, 0.f};

    for (int ks = 0; ks < 8; ++ks) {
        const int kk = ks * 32 + q * 8;
        bf16x8 af = {0, 0, 0, 0, 0, 0, 0, 0};
        if (rowok) {
            if (isbf) {
                const unsigned short* xp = (const unsigned short*)Xg + (size_t)row * NFEAT + kk;
                ushort4 lo = *(const ushort4*)xp;
                ushort4 hi = *(const ushort4*)(xp + 4);
                af[0] = (short)lo.x; af[1] = (short)lo.y; af[2] = (short)lo.z; af[3] = (short)lo.w;
                af[4] = (short)hi.x; af[5] = (short)hi.y; af[6] = (short)hi.z; af[7] = (short)hi.w;
            } else {
                const float* xp = (const float*)Xg + (size_t)row * NFEAT + kk;
                float4 f0 = *(const float4*)xp;
                float4 f1 = *(const float4*)(xp + 4);
                af[0] = (short)f2bf(f0.x); af[1] = (short)f2bf(f0.y);
                af[2] = (short)f2bf(f0.z); af[3] = (short)f2bf(f0.w);
                af[4] = (short)f2bf(f1.x); af[5] = (short)f2bf(f1.y);
                af[6] = (short)f2bf(f1.z); af[7] = (short)f2bf(f1.w);
            }
        }
        const unsigned short* wbase = &Ws[(ks * 4) * 512 + lane * 8];
        bf16x8 b0 = *(const bf16x8*)(wbase);
        bf16x8 b1 = *(const bf16x8*)(wbase + 512);
        bf16x8 b2 = *(const bf16x8*)(wbase + 1024);
        bf16x8 b3 = *(const bf16x8*)(wbase + 1536);
        acc0 = __builtin_amdgcn_mfma_f32_16x16x32_bf16(af, b0, acc0, 0, 0, 0);
        acc1 = __builtin_amdgcn_mfma_f32_16x16x32_bf16(af, b1, acc1, 0, 0, 0);
        acc2 = __builtin_amdgcn_mfma_f32_16x16x32_bf16(af, b2, acc2, 0, 0, 0);
        acc3 = __builtin_amdgcn_mfma_f32_16x16x32_bf16(af, b3, acc3, 0, 0, 0);
    }

    // C/D layout: col = lane&15, row = q*4 + reg
    const int rowbase = blockIdx.x * 64 + wv * 16 + q * 4;
#pragma unroll
    for (int i = 0; i < 4; ++i) {
        int gr = rowbase + i;
        if (gr < N) {
            unsigned short* yp = Yb + (size_t)gr * NCLS + m;
            yp[0]  = f2bf(acc0[i]);
            yp[16] = f2bf(acc1[i]);
            yp[32] = f2bf(acc2[i]);
            yp[48] = f2bf(acc3[i]);
        }
    }
}

// ---------- propagation hop: one wave per node, lane = feature ----------
// out[d] = dinv[d] * ( dinv[d]*Y[d] + sum_s dinv[s]*Y[s] )
__launch_bounds__(256)
__global__ void k_prop(const unsigned short* __restrict__ Yin,  // bf16 [N][64]
                       const int* __restrict__ ell, const int* __restrict__ cnt,
                       const float* __restrict__ dinv,
                       unsigned short* __restrict__ Ybout,      // bf16, hops 1-2
                       float* __restrict__ outf,                // fp32, last hop
                       const float* __restrict__ bias, int N) {
    int node = blockIdx.x * 4 + (threadIdx.x >> 6);
    if (node >= N) return;
    int lane = threadIdx.x & 63;
    int deg = cnt[node];
    if (deg > ELLW) deg = ELLW;
    float dn = dinv[node];
    float a0 = dn * bf2f(Yin[(size_t)node * NCLS + lane]);  // self
    float a1 = 0.f, a2 = 0.f, a3 = 0.f;
    const int* erow = ell + (size_t)node * ELLW;
    int e = 0;
    for (; e + 4 <= deg; e += 4) {
        int4 s4 = *(const int4*)(erow + e);
        int s0 = __builtin_amdgcn_readfirstlane(s4.x);
        int s1 = __builtin_amdgcn_readfirstlane(s4.y);
        int s2 = __builtin_amdgcn_readfirstlane(s4.z);
        int s3 = __builtin_amdgcn_readfirstlane(s4.w);
        float w0 = dinv[s0], w1 = dinv[s1], w2 = dinv[s2], w3 = dinv[s3];
        float y0 = bf2f(Yin[(size_t)s0 * NCLS + lane]);
        float y1 = bf2f(Yin[(size_t)s1 * NCLS + lane]);
        float y2 = bf2f(Yin[(size_t)s2 * NCLS + lane]);
        float y3 = bf2f(Yin[(size_t)s3 * NCLS + lane]);
        a0 = fmaf(w0, y0, a0);
        a1 = fmaf(w1, y1, a1);
        a2 = fmaf(w2, y2, a2);
        a3 = fmaf(w3, y3, a3);
    }
    for (; e < deg; ++e) {
        int s = __builtin_amdgcn_readfirstlane(erow[e]);
        a0 = fmaf(dinv[s], bf2f(Yin[(size_t)s * NCLS + lane]), a0);
    }
    float acc = dn * ((a0 + a1) + (a2 + a3));
    if (outf) {
        outf[(size_t)node * NCLS + lane] = acc + bias[lane];
    } else {
        Ybout[(size_t)node * NCLS + lane] = f2bf(acc);
    }
}

extern "C" void kernel_launch(void* const* d_in, const int* in_sizes, int n_in,
                              void* d_out, int out_size, void* d_ws, size_t ws_size,
                              hipStream_t stream) {
    const void* X  = d_in[0];
    const void* EI = d_in[1];
    const void* W  = d_in[2];
    const void* B  = d_in[3];
    float* out = (float*)d_out;

    const int N = in_sizes[0] / NFEAT;  // 50000
    const int twoE = in_sizes[1];       // 1,600,000
    const int E = twoE / 2;             // 800,000

    // ---- carve workspace (256B aligned) ----
    char* p = (char*)d_ws;
    auto alloc = [&](size_t bytes) -> char* {
        char* q = p;
        p += (bytes + 255) & ~(size_t)255;
        return q;
    };
    int*   flag   = (int*)alloc(4);
    int*   fflag  = (int*)alloc(4);
    int*   cnt    = (int*)alloc((size_t)N * 4);
    float* dinv   = (float*)alloc((size_t)N * 4);
    unsigned short* Wt = (unsigned short*)alloc((size_t)NFEAT * NCLS * 2);  // bf16 [n][k]
    float* bc     = (float*)alloc((size_t)NCLS * 4);
    int*   ell    = (int*)alloc((size_t)N * ELLW * 4);          // 12.8 MB
    unsigned short* Y0 = (unsigned short*)alloc((size_t)N * NCLS * 2);  // bf16
    unsigned short* Y1 = (unsigned short*)alloc((size_t)N * NCLS * 2);  // bf16

    hipMemsetAsync(cnt, 0, (size_t)N * 4, stream);

    k_detect2<<<2, 256, 0, stream>>>(EI, twoE, N, (const unsigned int*)X,
                                     in_sizes[0] / 2, flag, fflag);
    k_wconv<<<(NFEAT * NCLS + NCLS + 255) / 256, 256, 0, stream>>>(W, B, fflag, Wt, bc);

    const int ngemm = (N + 63) / 64;        // 782
    const int nbuild = (E + 255) / 256;     // 3125
    k_fused<<<ngemm + nbuild, 256, 0, stream>>>(X, Wt, Y0, N, fflag,
                                                EI, E, flag, cnt, ell, ngemm);
    k_dinv<<<(N + 255) / 256, 256, 0, stream>>>(cnt, dinv, N);

    int nb_p = (N + 3) / 4;
    k_prop<<<nb_p, 256, 0, stream>>>(Y0, ell, cnt, dinv, Y1, nullptr, nullptr, N);
    k_prop<<<nb_p, 256, 0, stream>>>(Y1, ell, cnt, dinv, Y0, nullptr, nullptr, N);
    k_prop<<<nb_p, 256, 0, stream>>>(Y0, ell, cnt, dinv, nullptr, out, bc, N);
}

// Round 5
// 254.465 us; speedup vs baseline: 1.5370x; 1.0136x over previous
//
#include <hip/hip_runtime.h>
#include <hip/hip_bf16.h>

// SGC: out = (D^-1/2 (A+I) D^-1/2)^3 X W + b
// R5: kill the cross-XCD random-write amplification in the adjacency build.
//   Phase P (fused with MFMA GEMM): partition edges into 8 dst-range buckets,
//     LDS-ranked per block -> contiguous coalesced bucket writes (no 8x amp).
//   Phase S: ELL scatter with bucket pinned to XCD via blockIdx&7 -> all writes
//     to one bucket's ELL region come from one XCD's L2 -> ~1x writeback.
//   Hops: bf16 Y, unroll-8 gather, nontemporal loads for stream-once data.

#define NFEAT 256
#define NCLS  64
#define ELLW  64       // slots per node; P(deg>=64) ~ 1e-18 for Binomial(E,1/N)
#define BCAP  110592   // per-bucket capacity (mean 100k, sigma ~331)
#define PCHUNK 2048    // edges per partition block

typedef __attribute__((ext_vector_type(8))) short bf16x8;
typedef __attribute__((ext_vector_type(4))) float f32x4;
typedef __attribute__((ext_vector_type(4))) int   i32x4;

__device__ __forceinline__ float bf2f(unsigned int u) {
    return __uint_as_float(u << 16);
}
__device__ __forceinline__ unsigned short f2bf(float f) {
    unsigned int u = __float_as_uint(f);
    unsigned int r = u + 0x7fffu + ((u >> 16) & 1u);  // RNE
    return (unsigned short)(r >> 16);
}

// ---------- fused dtype detection: block 0 = edges (int64 vs int32),
// ----------                        block 1 = floats (fp32 vs bf16) ----------
__global__ void k_detect2(const void* ei, int twoE, int nnodes,
                          const unsigned int* __restrict__ x, int nwords,
                          int* flag, int* fflag) {
    __shared__ int acc;
    if (threadIdx.x == 0) acc = 0;
    __syncthreads();
    if (blockIdx.x == 0) {
        const long long* p = (const long long*)ei;
        int nchk = 2048;
        if (nchk > twoE / 2) nchk = twoE / 2;
        int bad = 0;
        for (int i = threadIdx.x; i < nchk; i += 256) {
            long long v = p[i];
            if (v < 0 || v >= (long long)nnodes) bad++;
        }
        if (bad) atomicAdd(&acc, bad);
        __syncthreads();
        if (threadIdx.x == 0) *flag = (acc == 0) ? 1 : 0;  // 1 = int64
    } else {
        int lim = nwords < 4096 ? nwords : 4096;
        int wild = 0;
        for (int i = threadIdx.x; i < lim; i += 256) {
            unsigned int lo = x[i] & 0xffffu;
            unsigned int expf = (lo >> 7) & 0xffu;
            if (expf >= 0x97u) wild++;  // fp32 mantissa noise read as bf16
        }
        if (wild) atomicAdd(&acc, wild);
        __syncthreads();
        if (threadIdx.x == 0) *fflag = (acc < 8) ? 1 : 0;  // 1 = bf16
    }
}

// ---------- W -> bf16 transposed [n][k] + bias fp32 ----------
__global__ void k_wconv(const void* __restrict__ Wg, const void* __restrict__ Bg,
                        const int* __restrict__ fflag,
                        unsigned short* __restrict__ Wt, float* __restrict__ bc) {
    int i = blockIdx.x * 256 + threadIdx.x;
    bool isbf = (*fflag != 0);
    if (i < NFEAT * NCLS) {
        int n = i >> 8, k = i & 255;  // Wt[n][k] = W[k][n]
        Wt[i] = isbf ? ((const unsigned short*)Wg)[k * NCLS + n]
                     : f2bf(((const float*)Wg)[k * NCLS + n]);
    }
    int j = i - NFEAT * NCLS;
    if (j >= 0 && j < NCLS) {
        bc[j] = isbf ? bf2f(((const unsigned short*)Bg)[j])
                     : ((const float*)Bg)[j];
    }
}

// ---------- dinv from final degree counts ----------
__global__ void k_dinv(const int* __restrict__ cnt, float* __restrict__ dinv, int n) {
    int i = blockIdx.x * blockDim.x + threadIdx.x;
    if (i < n) dinv[i] = 1.0f / sqrtf((float)(cnt[i] + 1));  // +1 = self loop
}

// ---------- fused: [0, ngemm) = MFMA GEMM blocks, [ngemm, ..) = partition ----------
__launch_bounds__(256)
__global__ void k_fused(const void* __restrict__ Xg,
                        const unsigned short* __restrict__ Wt,  // [n][k] bf16
                        unsigned short* __restrict__ Yb,        // out bf16 [N][64]
                        int N, const int* __restrict__ fflag,
                        const void* __restrict__ ei, int E, const int* __restrict__ flag,
                        int2* __restrict__ bucket, int* __restrict__ gcur,
                        int ngemm) {
    const int t = threadIdx.x;

    if (blockIdx.x >= ngemm) {
        // ---------------- partition path: edges -> 8 dst-range buckets ----------------
        __shared__ int hist[8], lbase[8], rank[8];
        if (t < 8) { hist[t] = 0; rank[t] = 0; }
        __syncthreads();
        const int base_e = (blockIdx.x - ngemm) * PCHUNK;
        const bool is64 = (*flag != 0);
        const float scale = 8.0f / (float)N;
        int sv[8], dv[8], bj[8];
#pragma unroll
        for (int i = 0; i < 8; ++i) {
            int e = base_e + t + i * 256;
            bj[i] = -1;
            if (e < E) {
                int ss, dd;
                if (is64) {
                    ss = (int)__builtin_nontemporal_load((const long long*)ei + e);
                    dd = (int)__builtin_nontemporal_load((const long long*)ei + E + e);
                } else {
                    ss = __builtin_nontemporal_load((const int*)ei + e);
                    dd = __builtin_nontemporal_load((const int*)ei + E + e);
                }
                int j = (int)((float)dd * scale);
                j = j < 0 ? 0 : (j > 7 ? 7 : j);
                sv[i] = ss; dv[i] = dd; bj[i] = j;
                atomicAdd(&hist[j], 1);
            }
        }
        __syncthreads();
        if (t < 8) lbase[t] = atomicAdd(&gcur[t], hist[t]);
        __syncthreads();
#pragma unroll
        for (int i = 0; i < 8; ++i) {
            if (bj[i] >= 0) {
                int r = atomicAdd(&rank[bj[i]], 1);
                int pos = lbase[bj[i]] + r;
                if (pos < BCAP)  // overflow astronomically unlikely; guard OOB
                    bucket[(size_t)bj[i] * BCAP + pos] = make_int2(sv[i], dv[i]);
            }
        }
        return;
    }

    // ---------------- GEMM path ----------------
    __shared__ unsigned short Ws[2048 * 8];  // 32 KB: 8 ks x 4 nt x 64 lanes x 8 bf16
    for (int it = 0; it < 8; ++it) {
        int idx = t + 256 * it;
        int lane_e = idx & 63;
        int nt = (idx >> 6) & 3;
        int ks = idx >> 8;
        int n = nt * 16 + (lane_e & 15);
        int k = ks * 32 + (lane_e >> 4) * 8;
        const unsigned short* srcp = Wt + n * 256 + k;
        ushort4 v0 = *(const ushort4*)srcp;
        ushort4 v1 = *(const ushort4*)(srcp + 4);
        unsigned short* dstp = &Ws[idx * 8];
        *(ushort4*)dstp = v0;
        *(ushort4*)(dstp + 4) = v1;
    }
    __syncthreads();

    const int wv = t >> 6, lane = t & 63;
    const int m = lane & 15, q = lane >> 4;
    const int row = blockIdx.x * 64 + wv * 16 + m;  // A-operand row for this lane
    const bool rowok = row < N;
    const bool isbf = (*fflag != 0);

    f32x4 acc0 = {0.f, 0.f, 0.f, 0.f};
    f32x4 acc1 = {0.f, 0.f, 0.f, 0.f};
    f32x4 acc2 = {0.f, 0.f, 0.f, 0.f};
    f32x4 acc3 = {0.f, 0.f, 0.f, 0.f};

    for (int ks = 0; ks < 8; ++ks) {
        const int kk = ks * 32 + q * 8;
        bf16x8 af = {0, 0, 0, 0, 0, 0, 0, 0};
        if (rowok) {
            if (isbf) {
                const i32x4* xp = (const i32x4*)((const unsigned short*)Xg + (size_t)row * NFEAT + kk);
                i32x4 raw = __builtin_nontemporal_load(xp);
#pragma unroll
                for (int h = 0; h < 4; ++h) {
                    af[2 * h]     = (short)(raw[h] & 0xffff);
                    af[2 * h + 1] = (short)(((unsigned int)raw[h]) >> 16);
                }
            } else {
                const i32x4* xp = (const i32x4*)((const float*)Xg + (size_t)row * NFEAT + kk);
                i32x4 r0 = __builtin_nontemporal_load(xp);
                i32x4 r1 = __builtin_nontemporal_load(xp + 1);
#pragma unroll
                for (int h = 0; h < 4; ++h) {
                    af[h]     = (short)f2bf(__int_as_float(r0[h]));
                    af[h + 4] = (short)f2bf(__int_as_float(r1[h]));
                }
            }
        }
        const unsigned short* wbase = &Ws[(ks * 4) * 512 + lane * 8];
        bf16x8 b0 = *(const bf16x8*)(wbase);
        bf16x8 b1 = *(const bf16x8*)(wbase + 512);
        bf16x8 b2 = *(const bf16x8*)(wbase + 1024);
        bf16x8 b3 = *(const bf16x8*)(wbase + 1536);
        acc0 = __builtin_amdgcn_mfma_f32_16x16x32_bf16(af, b0, acc0, 0, 0, 0);
        acc1 = __builtin_amdgcn_mfma_f32_16x16x32_bf16(af, b1, acc1, 0, 0, 0);
        acc2 = __builtin_amdgcn_mfma_f32_16x16x32_bf16(af, b2, acc2, 0, 0, 0);
        acc3 = __builtin_amdgcn_mfma_f32_16x16x32_bf16(af, b3, acc3, 0, 0, 0);
    }

    // C/D layout: col = lane&15, row = q*4 + reg
    const int rowbase = blockIdx.x * 64 + wv * 16 + q * 4;
#pragma unroll
    for (int i = 0; i < 4; ++i) {
        int gr = rowbase + i;
        if (gr < N) {
            unsigned short* yp = Yb + (size_t)gr * NCLS + m;
            yp[0]  = f2bf(acc0[i]);
            yp[16] = f2bf(acc1[i]);
            yp[32] = f2bf(acc2[i]);
            yp[48] = f2bf(acc3[i]);
        }
    }
}

// ---------- ELL scatter, XCD-pinned: block b handles bucket b&7 ----------
__launch_bounds__(256)
__global__ void k_scatter_ell(const int2* __restrict__ bucket, const int* __restrict__ gcnt,
                              int* __restrict__ cnt, int* __restrict__ ell) {
    const int j = blockIdx.x & 7;                       // bucket == XCD (heuristic)
    const int idx = (blockIdx.x >> 3) * 256 + threadIdx.x;
    if (idx >= gcnt[j]) return;
    long long v = __builtin_nontemporal_load((const long long*)(bucket + (size_t)j * BCAP) + idx);
    int s = (int)v;
    int d = (int)(v >> 32);
    int r = atomicAdd(&cnt[d], 1);
    if (r < ELLW) ell[(size_t)d * ELLW + r] = s;
}

// ---------- propagation hop: one wave per node, lane = feature ----------
// out[d] = dinv[d] * ( dinv[d]*Y[d] + sum_s dinv[s]*Y[s] )
__launch_bounds__(256)
__global__ void k_prop(const unsigned short* __restrict__ Yin,  // bf16 [N][64]
                       const int* __restrict__ ell, const int* __restrict__ cnt,
                       const float* __restrict__ dinv,
                       unsigned short* __restrict__ Ybout,      // bf16, hops 1-2
                       float* __restrict__ outf,                // fp32, last hop
                       const float* __restrict__ bias, int N) {
    int node = blockIdx.x * 4 + (threadIdx.x >> 6);
    if (node >= N) return;
    int lane = threadIdx.x & 63;
    int deg = cnt[node];
    if (deg > ELLW) deg = ELLW;
    float dn = dinv[node];
    float a0 = dn * bf2f(Yin[(size_t)node * NCLS + lane]);  // self
    float a1 = 0.f, a2 = 0.f, a3 = 0.f;
    const int* erow = ell + (size_t)node * ELLW;
    int e = 0;
    for (; e + 8 <= deg; e += 8) {
        i32x4 sa = __builtin_nontemporal_load((const i32x4*)(erow + e));
        i32x4 sb = __builtin_nontemporal_load((const i32x4*)(erow + e + 4));
        int s0 = __builtin_amdgcn_readfirstlane(sa[0]);
        int s1 = __builtin_amdgcn_readfirstlane(sa[1]);
        int s2 = __builtin_amdgcn_readfirstlane(sa[2]);
        int s3 = __builtin_amdgcn_readfirstlane(sa[3]);
        int s4 = __builtin_amdgcn_readfirstlane(sb[0]);
        int s5 = __builtin_amdgcn_readfirstlane(sb[1]);
        int s6 = __builtin_amdgcn_readfirstlane(sb[2]);
        int s7 = __builtin_amdgcn_readfirstlane(sb[3]);
        float y0 = bf2f(Yin[(size_t)s0 * NCLS + lane]);
        float y1 = bf2f(Yin[(size_t)s1 * NCLS + lane]);
        float y2 = bf2f(Yin[(size_t)s2 * NCLS + lane]);
        float y3 = bf2f(Yin[(size_t)s3 * NCLS + lane]);
        float y4 = bf2f(Yin[(size_t)s4 * NCLS + lane]);
        float y5 = bf2f(Yin[(size_t)s5 * NCLS + lane]);
        float y6 = bf2f(Yin[(size_t)s6 * NCLS + lane]);
        float y7 = bf2f(Yin[(size_t)s7 * NCLS + lane]);
        a0 = fmaf(dinv[s0], y0, a0);
        a1 = fmaf(dinv[s1], y1, a1);
        a2 = fmaf(dinv[s2], y2, a2);
        a3 = fmaf(dinv[s3], y3, a3);
        a0 = fmaf(dinv[s4], y4, a0);
        a1 = fmaf(dinv[s5], y5, a1);
        a2 = fmaf(dinv[s6], y6, a2);
        a3 = fmaf(dinv[s7], y7, a3);
    }
    for (; e + 4 <= deg; e += 4) {
        i32x4 sa = __builtin_nontemporal_load((const i32x4*)(erow + e));
        int s0 = __builtin_amdgcn_readfirstlane(sa[0]);
        int s1 = __builtin_amdgcn_readfirstlane(sa[1]);
        int s2 = __builtin_amdgcn_readfirstlane(sa[2]);
        int s3 = __builtin_amdgcn_readfirstlane(sa[3]);
        float y0 = bf2f(Yin[(size_t)s0 * NCLS + lane]);
        float y1 = bf2f(Yin[(size_t)s1 * NCLS + lane]);
        float y2 = bf2f(Yin[(size_t)s2 * NCLS + lane]);
        float y3 = bf2f(Yin[(size_t)s3 * NCLS + lane]);
        a0 = fmaf(dinv[s0], y0, a0);
        a1 = fmaf(dinv[s1], y1, a1);
        a2 = fmaf(dinv[s2], y2, a2);
        a3 = fmaf(dinv[s3], y3, a3);
    }
    for (; e < deg; ++e) {
        int s = __builtin_amdgcn_readfirstlane(erow[e]);
        a0 = fmaf(dinv[s], bf2f(Yin[(size_t)s * NCLS + lane]), a0);
    }
    float acc = dn * ((a0 + a1) + (a2 + a3));
    if (outf) {
        outf[(size_t)node * NCLS + lane] = acc + bias[lane];
    } else {
        Ybout[(size_t)node * NCLS + lane] = f2bf(acc);
    }
}

extern "C" void kernel_launch(void* const* d_in, const int* in_sizes, int n_in,
                              void* d_out, int out_size, void* d_ws, size_t ws_size,
                              hipStream_t stream) {
    const void* X  = d_in[0];
    const void* EI = d_in[1];
    const void* W  = d_in[2];
    const void* B  = d_in[3];
    float* out = (float*)d_out;

    const int N = in_sizes[0] / NFEAT;  // 50000
    const int twoE = in_sizes[1];       // 1,600,000
    const int E = twoE / 2;             // 800,000

    // ---- carve workspace (256B aligned) ----
    char* p = (char*)d_ws;
    auto alloc = [&](size_t bytes) -> char* {
        char* q = p;
        p += (bytes + 255) & ~(size_t)255;
        return q;
    };
    int*   flag   = (int*)alloc(4);
    int*   fflag  = (int*)alloc(4);
    int*   cnt    = (int*)alloc((size_t)(N + 8) * 4);   // cnt[N] then gcur[8]
    float* dinv   = (float*)alloc((size_t)N * 4);
    unsigned short* Wt = (unsigned short*)alloc((size_t)NFEAT * NCLS * 2);  // bf16 [n][k]
    float* bc     = (float*)alloc((size_t)NCLS * 4);
    int2*  bucket = (int2*)alloc((size_t)8 * BCAP * 8);  // 7.1 MB
    int*   ell    = (int*)alloc((size_t)N * ELLW * 4);   // 12.8 MB
    unsigned short* Y0 = (unsigned short*)alloc((size_t)N * NCLS * 2);  // bf16
    unsigned short* Y1 = (unsigned short*)alloc((size_t)N * NCLS * 2);  // bf16

    int* gcur = cnt + N;

    hipMemsetAsync(cnt, 0, (size_t)(N + 8) * 4, stream);

    k_detect2<<<2, 256, 0, stream>>>(EI, twoE, N, (const unsigned int*)X,
                                     in_sizes[0] / 2, flag, fflag);
    k_wconv<<<(NFEAT * NCLS + NCLS + 255) / 256, 256, 0, stream>>>(W, B, fflag, Wt, bc);

    const int ngemm = (N + 63) / 64;            // 782
    const int npart = (E + PCHUNK - 1) / PCHUNK; // 391
    k_fused<<<ngemm + npart, 256, 0, stream>>>(X, Wt, Y0, N, fflag,
                                               EI, E, flag, bucket, gcur, ngemm);

    k_scatter_ell<<<8 * (BCAP / 256), 256, 0, stream>>>(bucket, gcur, cnt, ell);
    k_dinv<<<(N + 255) / 256, 256, 0, stream>>>(cnt, dinv, N);

    int nb_p = (N + 3) / 4;
    k_prop<<<nb_p, 256, 0, stream>>>(Y0, ell, cnt, dinv, Y1, nullptr, nullptr, N);
    k_prop<<<nb_p, 256, 0, stream>>>(Y1, ell, cnt, dinv, Y0, nullptr, nullptr, N);
    k_prop<<<nb_p, 256, 0, stream>>>(Y0, ell, cnt, dinv, nullptr, out, bc, N);
}